// Round 5
// baseline (314.547 us; speedup 1.0000x reference)
//
#include <hip/hip_runtime.h>
#include <hip/hip_bf16.h>
#include <stdint.h>

#define B_ 4
#define S_ 2048
#define H_ 1024

typedef __attribute__((ext_vector_type(4))) float f32x4;
typedef __attribute__((ext_vector_type(8))) short bf16x8;

#define AS1C(p) ((const __attribute__((address_space(1))) void*)(p))
#define AS3(p)  ((__attribute__((address_space(3))) void*)(p))

// ------- one-shot prep: convert X, Wq|Wk|Wv, pack biases, zero rsum -------
// grid-stride @2048 blocks (r4-proven: ~10 us faster than the 11k-block shape)
__global__ __launch_bounds__(256)
void prep_k(const float* __restrict__ X,
            const float* __restrict__ Wq, const float* __restrict__ Wk,
            const float* __restrict__ Wv,
            const float* __restrict__ bq, const float* __restrict__ bk,
            const float* __restrict__ bv,
            __hip_bfloat16* __restrict__ Xb, __hip_bfloat16* __restrict__ Wall,
            float* __restrict__ ball, float* __restrict__ rsum)
{
    const int NX = B_ * S_ * H_ / 4;   // float4 count of X
    const int NW = H_ * H_ / 4;        // float4 count of one W (2^18)
    const int TOT = NX + 3 * NW + 3 * H_ / 4 + B_ * S_ / 4;
    const int stride = gridDim.x * blockDim.x;
    for (int i = blockIdx.x * blockDim.x + threadIdx.x; i < TOT; i += stride) {
        if (i < NX + 3 * NW) {
            const float* src; uint64_t* dst; int li;
            if (i < NX) { src = X; dst = (uint64_t*)Xb; li = i; }
            else {
                int j = i - NX;
                int wsel = j / NW; li = j - wsel * NW;
                src = (wsel == 0) ? Wq : (wsel == 1) ? Wk : Wv;
                dst = (uint64_t*)Wall + (size_t)wsel * NW;
            }
            float4 v = ((const float4*)src)[li];
            union { __hip_bfloat16 h[4]; uint64_t u; } o;
            o.h[0] = __float2bfloat16(v.x);
            o.h[1] = __float2bfloat16(v.y);
            o.h[2] = __float2bfloat16(v.z);
            o.h[3] = __float2bfloat16(v.w);
            dst[li] = o.u;
        } else {
            int j = i - (NX + 3 * NW);
            if (j < 3 * H_ / 4) {                    // bias pack (float4)
                int bsel = j >> 8;
                int off  = j & 255;
                const float* src = (bsel == 0) ? bq : (bsel == 1) ? bk : bv;
                ((float4*)ball)[j] = ((const float4*)src)[off];
            } else {                                  // zero rsum (float4)
                int j2 = j - 3 * H_ / 4;
                ((float4*)rsum)[j2] = make_float4(0.f, 0.f, 0.f, 0.f);
            }
        }
    }
}

// ------- B-transposed bf16 GEMM, 16x16x32 MFMA, BK=64, single-buffer -------
// r0-proven body (r5: T1 swizzle REVERTED — it raised FETCH 72->85MB, +3us).
template<int BN, int MINW, bool OUT_BF16, bool HAS_BIAS, bool V_SPLIT, bool EXP_SUM, bool ROWDIV>
__global__ __launch_bounds__(256, MINW)
void gemm_bt(const __hip_bfloat16* __restrict__ A, int lda, long long aBatch,
             const __hip_bfloat16* __restrict__ B, int ldb, long long bBatch,
             const float* __restrict__ bias,
             void* __restrict__ Cout, int ldc, long long cBatch,
             __hip_bfloat16* __restrict__ vtrans, float* __restrict__ rsum,
             int M, int N, int K, float scale)
{
    constexpr int FJ = BN / 32;
    constexpr int SN = BN / 32;
    __shared__ __hip_bfloat16 lA[128 * 64];
    __shared__ __hip_bfloat16 lB[BN * 64];

    const int t  = threadIdx.x;
    const int bz = blockIdx.z;
    A += (long long)bz * aBatch;
    B += (long long)bz * bBatch;
    const int bm = blockIdx.y * 128;
    const int bn = blockIdx.x * BN;

    const int wave = t >> 6;
    const int lane = t & 63;
    const int wm = (wave & 1) * 64;
    const int wn = (wave >> 1) * (BN / 2);
    const int lm = lane & 15;
    const int kq = lane >> 4;
    const int cro = lm & 7;

    f32x4 acc[4][FJ] = {};

    const int srow = t >> 3;
    const int swz  = ((t & 7) ^ ((t >> 3) & 7)) * 8;
    const __hip_bfloat16* gA = A + (long long)(bm + srow) * lda + swz;
    const __hip_bfloat16* gB = B + (long long)(bn + srow) * ldb + swz;
    __hip_bfloat16* sA = lA + t * 8;
    __hip_bfloat16* sB = lB + t * 8;

    for (int k0 = 0; k0 < K; k0 += 64) {
        __syncthreads();
#pragma unroll
        for (int s = 0; s < 4; ++s)
            __builtin_amdgcn_global_load_lds(AS1C(gA + (long long)s * 32 * lda + k0),
                                             AS3(sA + s * 2048), 16, 0, 0);
#pragma unroll
        for (int s = 0; s < SN; ++s)
            __builtin_amdgcn_global_load_lds(AS1C(gB + (long long)s * 32 * ldb + k0),
                                             AS3(sB + s * 2048), 16, 0, 0);
        __syncthreads();

#pragma unroll
        for (int ks = 0; ks < 2; ++ks) {
            bf16x8 af[4], bfr[FJ];
            const int ch = ((ks * 4 + kq) ^ cro) * 8;
#pragma unroll
            for (int i = 0; i < 4; ++i)
                af[i] = *(const bf16x8*)(lA + (wm + i * 16 + lm) * 64 + ch);
#pragma unroll
            for (int j = 0; j < FJ; ++j)
                bfr[j] = *(const bf16x8*)(lB + (wn + j * 16 + lm) * 64 + ch);
#pragma unroll
            for (int i = 0; i < 4; ++i)
#pragma unroll
                for (int j = 0; j < FJ; ++j)
                    acc[i][j] = __builtin_amdgcn_mfma_f32_16x16x32_bf16(af[i], bfr[j], acc[i][j], 0, 0, 0);
        }
    }

    // epilogue: C/D layout col = lane&15, row = (lane>>4)*4 + reg  [m89]
    const bool vmode = V_SPLIT && (bn >= 2 * H_);
    const int r0q = kq * 4;

    if (EXP_SUM) {
#pragma unroll
        for (int i = 0; i < 4; ++i) {
            const int rowb = bm + wm + i * 16 + r0q;
            float ps[4] = {0.f, 0.f, 0.f, 0.f};
#pragma unroll
            for (int j = 0; j < FJ; ++j) {
                const int col = bn + wn + j * 16 + lm;
#pragma unroll
                for (int r = 0; r < 4; ++r) {
                    float e = __expf(acc[i][j][r] * scale);
                    ps[r] += e;
                    ((__hip_bfloat16*)Cout)[(long long)bz * cBatch +
                        (long long)(rowb + r) * ldc + col] = __float2bfloat16(e);
                }
            }
#pragma unroll
            for (int r = 0; r < 4; ++r) {
#pragma unroll
                for (int m = 1; m < 16; m <<= 1)
                    ps[r] += __shfl_xor(ps[r], m);
            }
            if (lm == 0) {
#pragma unroll
                for (int r = 0; r < 4; ++r)
                    atomicAdd(rsum + bz * S_ + rowb + r, ps[r]);
            }
        }
        return;
    }

#pragma unroll
    for (int i = 0; i < 4; ++i) {
        const int rowb = bm + wm + i * 16 + r0q;
        float inv[4];
        if (ROWDIV) {
            float4 rs = *(const float4*)(rsum + bz * S_ + rowb);
            inv[0] = 1.0f / rs.x; inv[1] = 1.0f / rs.y;
            inv[2] = 1.0f / rs.z; inv[3] = 1.0f / rs.w;
        }
#pragma unroll
        for (int j = 0; j < FJ; ++j) {
            const int col = bn + wn + j * 16 + lm;
            float bvv = 0.0f;
            if (HAS_BIAS) bvv = bias[col];
            if (!vmode) {
#pragma unroll
                for (int r = 0; r < 4; ++r) {
                    float val = ROWDIV ? acc[i][j][r] * inv[r]
                                       : acc[i][j][r] * scale + bvv;
                    long long idx = (long long)bz * cBatch + (long long)(rowb + r) * ldc + col;
                    if (OUT_BF16) ((__hip_bfloat16*)Cout)[idx] = __float2bfloat16(val);
                    else          ((float*)Cout)[idx] = val;
                }
            } else {
                // vtrans[b][e][s]: b = rowb>>11, s = rowb&2047 (+r contiguous), e = col-2048
                const long long ebase = (long long)((rowb >> 11) * H_ + col - 2 * H_) * S_;
                union { ushort4 u; __hip_bfloat16 h[4]; } o;
#pragma unroll
                for (int r = 0; r < 4; ++r)
                    o.h[r] = __float2bfloat16(acc[i][j][r] + bvv);
                *(ushort4*)(vtrans + ebase + (rowb & 2047)) = o.u;
            }
        }
    }
}

// =====================================================================
// r5: merged scores + V-projection dispatch (latency-shadow co-scheduling).
// 1536 blocks: id%3==0 -> V-proj role (512 blocks, X@Wv^T -> vtb transposed),
// else -> exp-scores role (1024 blocks, exp(Q@K^T/32) -> sc, rsum atomics).
// Both roles are independent (V-proj needs only Xb/Wall; scores needs qk
// from the prior QK-proj dispatch). scores is latency-bound (506 TF, all
// pipes <50%) -> V-proj work fills the idle issue slots on every CU.
// Core loop = the r0-proven 128x128 BK=64 gemm_bt body (runtime lda/ldb).
// =====================================================================
__global__ __launch_bounds__(256, 4)
void sv_k(const __hip_bfloat16* __restrict__ Xb,
          const __hip_bfloat16* __restrict__ Wall,
          const float* __restrict__ ball,
          const __hip_bfloat16* __restrict__ qk,
          __hip_bfloat16* __restrict__ sc,
          __hip_bfloat16* __restrict__ vtb,
          float* __restrict__ rsum)
{
    __shared__ __hip_bfloat16 lA[128 * 64];
    __shared__ __hip_bfloat16 lB[128 * 64];

    const int t  = threadIdx.x;
    const int id = blockIdx.x;
    const bool vrole = (id % 3) == 0;

    const __hip_bfloat16 *A, *Bm;
    int lda, ldb, bm, bn, bz = 0;
    if (vrole) {
        const int v = id / 3;                 // 0..511
        bm = (v >> 3) * 128;                  // 64 row tiles (flattened B*S)
        bn = 2 * H_ + (v & 7) * 128;          // cols 2048..3071 of Wall
        A  = Xb;   lda = H_;
        Bm = Wall; ldb = H_;
    } else {
        const int s = id - id / 3 - 1;        // 0..1023
        bz = s >> 8;
        bm = ((s >> 4) & 15) * 128;
        bn = (s & 15) * 128;
        A  = qk      + (long long)bz * S_ * 2 * H_;
        Bm = qk + H_ + (long long)bz * S_ * 2 * H_;
        lda = 2 * H_; ldb = 2 * H_;
    }

    const int wave = t >> 6;
    const int lane = t & 63;
    const int wm = (wave & 1) * 64;
    const int wn = (wave >> 1) * 64;
    const int lm = lane & 15;
    const int kq = lane >> 4;
    const int cro = lm & 7;

    f32x4 acc[4][4] = {};

    const int srow = t >> 3;
    const int swz  = ((t & 7) ^ ((t >> 3) & 7)) * 8;
    const __hip_bfloat16* gA = A  + (long long)(bm + srow) * lda + swz;
    const __hip_bfloat16* gB = Bm + (long long)(bn + srow) * ldb + swz;
    __hip_bfloat16* sA = lA + t * 8;
    __hip_bfloat16* sB = lB + t * 8;

    for (int k0 = 0; k0 < H_; k0 += 64) {
        __syncthreads();
#pragma unroll
        for (int s = 0; s < 4; ++s)
            __builtin_amdgcn_global_load_lds(AS1C(gA + (long long)s * 32 * lda + k0),
                                             AS3(sA + s * 2048), 16, 0, 0);
#pragma unroll
        for (int s = 0; s < 4; ++s)
            __builtin_amdgcn_global_load_lds(AS1C(gB + (long long)s * 32 * ldb + k0),
                                             AS3(sB + s * 2048), 16, 0, 0);
        __syncthreads();

#pragma unroll
        for (int ks = 0; ks < 2; ++ks) {
            bf16x8 af[4], bfr[4];
            const int ch = ((ks * 4 + kq) ^ cro) * 8;
#pragma unroll
            for (int i = 0; i < 4; ++i)
                af[i] = *(const bf16x8*)(lA + (wm + i * 16 + lm) * 64 + ch);
#pragma unroll
            for (int j = 0; j < 4; ++j)
                bfr[j] = *(const bf16x8*)(lB + (wn + j * 16 + lm) * 64 + ch);
#pragma unroll
            for (int i = 0; i < 4; ++i)
#pragma unroll
                for (int j = 0; j < 4; ++j)
                    acc[i][j] = __builtin_amdgcn_mfma_f32_16x16x32_bf16(af[i], bfr[j], acc[i][j], 0, 0, 0);
        }
    }

    const int r0q = kq * 4;
    if (vrole) {
        // vtrans[b][e][s]: b = rowb>>11, s = rowb&2047 (+r contiguous), e = col-2048
#pragma unroll
        for (int i = 0; i < 4; ++i) {
            const int rowb = bm + wm + i * 16 + r0q;
#pragma unroll
            for (int j = 0; j < 4; ++j) {
                const int col = bn + wn + j * 16 + lm;
                const float bvv = ball[col];
                const long long ebase = (long long)((rowb >> 11) * H_ + col - 2 * H_) * S_;
                union { ushort4 u; __hip_bfloat16 h[4]; } o;
#pragma unroll
                for (int r = 0; r < 4; ++r)
                    o.h[r] = __float2bfloat16(acc[i][j][r] + bvv);
                *(ushort4*)(vtb + ebase + (rowb & 2047)) = o.u;
            }
        }
    } else {
#pragma unroll
        for (int i = 0; i < 4; ++i) {
            const int rowb = bm + wm + i * 16 + r0q;
            float ps[4] = {0.f, 0.f, 0.f, 0.f};
#pragma unroll
            for (int j = 0; j < 4; ++j) {
                const int col = bn + wn + j * 16 + lm;
#pragma unroll
                for (int r = 0; r < 4; ++r) {
                    float e = __expf(acc[i][j][r] * 0.03125f);
                    ps[r] += e;
                    sc[(long long)bz * S_ * S_ + (long long)(rowb + r) * S_ + col] =
                        __float2bfloat16(e);
                }
            }
#pragma unroll
            for (int r = 0; r < 4; ++r) {
#pragma unroll
                for (int m = 1; m < 16; m <<= 1)
                    ps[r] += __shfl_xor(ps[r], m);
            }
            if (lm == 0) {
#pragma unroll
                for (int r = 0; r < 4; ++r)
                    atomicAdd(rsum + bz * S_ + rowb + r, ps[r]);
            }
        }
    }
}

// ---------------- launcher ----------------
extern "C" void kernel_launch(void* const* d_in, const int* in_sizes, int n_in,
                              void* d_out, int out_size, void* d_ws, size_t ws_size,
                              hipStream_t stream)
{
    const float* X  = (const float*)d_in[0];
    const float* Wq = (const float*)d_in[1];
    const float* bq = (const float*)d_in[2];
    const float* Wk = (const float*)d_in[3];
    const float* bk = (const float*)d_in[4];
    const float* Wv = (const float*)d_in[5];
    const float* bv = (const float*)d_in[6];
    float* out = (float*)d_out;

    char* w = (char*)d_ws;
    const size_t MB = 1ull << 20;
    // Merged layout (needs 113 MB; Xb/Wall stay LIVE through the merged pass):
    //   [0,16)    Xb bf16 [8192,1024]
    //   [16,22)   Wall bf16 [3072,1024]
    //   [22,23)   ball fp32 [3072]
    //   [32,64)   qk  bf16 [8192,2048]  (Q cols 0..1023, K cols 1024..2047)
    //   [64,80)   vtb bf16 [B,H,S]
    //   [80,112)  sc  exp-scores bf16 [B,S,S]
    //   [112MB,+32KB) rsum fp32 [B*S]
    // Fallback (< 113 MB): r0 layout — sc overlays dead Xb/Wall, rsum @80MB,
    // serial QKV -> scores.
    const bool big = ws_size >= 113 * MB;
    __hip_bfloat16* Xb   = (__hip_bfloat16*)(w + 0);
    __hip_bfloat16* Wall = (__hip_bfloat16*)(w + 16 * MB);
    float*          ball = (float*)        (w + 22 * MB);
    __hip_bfloat16* qk   = (__hip_bfloat16*)(w + 32 * MB);
    __hip_bfloat16* vtb  = (__hip_bfloat16*)(w + 64 * MB);
    __hip_bfloat16* sc   = big ? (__hip_bfloat16*)(w + 80 * MB) : (__hip_bfloat16*)(w + 0);
    float*          rsum = big ? (float*)(w + 112 * MB)         : (float*)(w + 80 * MB);

    // 1. prep (X/W convert + bias pack + rsum zero) — grid-stride @2048 blocks
    prep_k<<<2048, 256, 0, stream>>>(X, Wq, Wk, Wv, bq, bk, bv,
                                     Xb, Wall, ball, rsum);

    if (big) {
        // 2. QK projection only (1024 blocks; MINW=4 -> exactly 1 round @4/CU)
        dim3 g1(2 * H_ / 128, (B_ * S_) / 128, 1);   // 16, 64
        gemm_bt<128, 4, true, true, true, false, false><<<g1, 256, 0, stream>>>(
            Xb, H_, 0, Wall, H_, 0, ball, qk, 2 * H_, 0, vtb, nullptr,
            B_ * S_, 2 * H_, H_, 1.0f);

        // 3. merged exp-scores (1024 blocks) + V-projection (512 blocks):
        //    V-proj fills scores' idle issue slots (scores is latency-bound).
        sv_k<<<1536, 256, 0, stream>>>(Xb, Wall, ball, qk, sc, vtb, rsum);
    } else {
        // 2. fused QKV projection (r0 path)
        dim3 g1(3 * H_ / 128, (B_ * S_) / 128, 1);
        gemm_bt<128, 1, true, true, true, false, false><<<g1, 256, 0, stream>>>(
            Xb, H_, 0, Wall, H_, 0, ball, qk, 2 * H_, 0, vtb, nullptr,
            B_ * S_, 3 * H_, H_, 1.0f);

        // 3. exp-scores (r0 path)
        dim3 g2(S_ / 128, S_ / 128, B_);
        gemm_bt<128, 4, true, false, false, true, false><<<g2, 256, 0, stream>>>(
            qk,      2 * H_, (long long)S_ * 2 * H_,
            qk + H_, 2 * H_, (long long)S_ * 2 * H_,
            nullptr, sc, S_, (long long)S_ * S_, nullptr, rsum, S_, S_, H_, 0.03125f);
    }

    // 4. out[b] = (exp-scores[b] @ vtb[b]^T) / rsum  (1024 blocks; MINW=4)
    dim3 g3(H_ / 64, S_ / 128, B_);
    gemm_bt<64, 4, false, false, false, false, true><<<g3, 256, 0, stream>>>(
        sc,  S_, (long long)S_ * S_,
        vtb, S_, (long long)H_ * S_,
        nullptr, out, H_, (long long)S_ * H_, nullptr, rsum, S_, H_, S_, 1.0f);
}

// Round 6
// 247.765 us; speedup vs baseline: 1.2695x; 1.2695x over previous
//
#include <hip/hip_runtime.h>
#include <hip/hip_bf16.h>
#include <stdint.h>

#define B_ 4
#define S_ 2048
#define H_ 1024

typedef __attribute__((ext_vector_type(4))) float f32x4;
typedef __attribute__((ext_vector_type(8))) short bf16x8;

#define AS1C(p) ((const __attribute__((address_space(1))) void*)(p))
#define AS3(p)  ((__attribute__((address_space(3))) void*)(p))

// ------- one-shot prep: convert X, Wq|Wk|Wv, pack biases, zero rsum -------
// grid-stride @2048 blocks (r4-proven: ~10 us faster than the 11k-block shape)
__global__ __launch_bounds__(256)
void prep_k(const float* __restrict__ X,
            const float* __restrict__ Wq, const float* __restrict__ Wk,
            const float* __restrict__ Wv,
            const float* __restrict__ bq, const float* __restrict__ bk,
            const float* __restrict__ bv,
            __hip_bfloat16* __restrict__ Xb, __hip_bfloat16* __restrict__ Wall,
            float* __restrict__ ball, float* __restrict__ rsum)
{
    const int NX = B_ * S_ * H_ / 4;   // float4 count of X
    const int NW = H_ * H_ / 4;        // float4 count of one W (2^18)
    const int TOT = NX + 3 * NW + 3 * H_ / 4 + B_ * S_ / 4;
    const int stride = gridDim.x * blockDim.x;
    for (int i = blockIdx.x * blockDim.x + threadIdx.x; i < TOT; i += stride) {
        if (i < NX + 3 * NW) {
            const float* src; uint64_t* dst; int li;
            if (i < NX) { src = X; dst = (uint64_t*)Xb; li = i; }
            else {
                int j = i - NX;
                int wsel = j / NW; li = j - wsel * NW;
                src = (wsel == 0) ? Wq : (wsel == 1) ? Wk : Wv;
                dst = (uint64_t*)Wall + (size_t)wsel * NW;
            }
            float4 v = ((const float4*)src)[li];
            union { __hip_bfloat16 h[4]; uint64_t u; } o;
            o.h[0] = __float2bfloat16(v.x);
            o.h[1] = __float2bfloat16(v.y);
            o.h[2] = __float2bfloat16(v.z);
            o.h[3] = __float2bfloat16(v.w);
            dst[li] = o.u;
        } else {
            int j = i - (NX + 3 * NW);
            if (j < 3 * H_ / 4) {                    // bias pack (float4)
                int bsel = j >> 8;
                int off  = j & 255;
                const float* src = (bsel == 0) ? bq : (bsel == 1) ? bk : bv;
                ((float4*)ball)[j] = ((const float4*)src)[off];
            } else {                                  // zero rsum (float4)
                int j2 = j - 3 * H_ / 4;
                ((float4*)rsum)[j2] = make_float4(0.f, 0.f, 0.f, 0.f);
            }
        }
    }
}

// ------- B-transposed bf16 GEMM, 16x16x32 MFMA, BK=64, single-buffer -------
// C[M,N] = scale * (A[M,K] @ B[N,K]^T) + bias[N]
// 128xBN block tile, 4 waves (2x2), wave tile 64 x BN/2.
// XOR chunk swizzle on staging+read: 0 LDS bank conflicts (r3-verified).
// r5 reverted the XCD swizzle (raised FETCH 72->85MB) and the sv_k merge
// (L2 thrash: FETCH 227MB, WRITE 257MB, 130us). This is the r0-proven body.
template<int BN, int MINW, bool OUT_BF16, bool HAS_BIAS, bool V_SPLIT, bool EXP_SUM, bool ROWDIV>
__global__ __launch_bounds__(256, MINW)
void gemm_bt(const __hip_bfloat16* __restrict__ A, int lda, long long aBatch,
             const __hip_bfloat16* __restrict__ B, int ldb, long long bBatch,
             const float* __restrict__ bias,
             void* __restrict__ Cout, int ldc, long long cBatch,
             __hip_bfloat16* __restrict__ vtrans, float* __restrict__ rsum,
             int M, int N, int K, float scale)
{
    constexpr int FJ = BN / 32;        // B-frags per wave (16-col units)
    constexpr int SN = BN / 32;        // B staging steps (32 rows each)
    __shared__ __hip_bfloat16 lA[128 * 64];
    __shared__ __hip_bfloat16 lB[BN * 64];

    const int t  = threadIdx.x;
    const int bz = blockIdx.z;
    A += (long long)bz * aBatch;
    B += (long long)bz * bBatch;
    const int bm = blockIdx.y * 128;
    const int bn = blockIdx.x * BN;

    const int wave = t >> 6;
    const int lane = t & 63;
    const int wm = (wave & 1) * 64;
    const int wn = (wave >> 1) * (BN / 2);
    const int lm = lane & 15;
    const int kq = lane >> 4;
    const int cro = lm & 7;

    f32x4 acc[4][FJ] = {};

    const int srow = t >> 3;                         // 0..31
    const int swz  = ((t & 7) ^ ((t >> 3) & 7)) * 8;
    const __hip_bfloat16* gA = A + (long long)(bm + srow) * lda + swz;
    const __hip_bfloat16* gB = B + (long long)(bn + srow) * ldb + swz;
    __hip_bfloat16* sA = lA + t * 8;
    __hip_bfloat16* sB = lB + t * 8;

    for (int k0 = 0; k0 < K; k0 += 64) {
        __syncthreads();
#pragma unroll
        for (int s = 0; s < 4; ++s)
            __builtin_amdgcn_global_load_lds(AS1C(gA + (long long)s * 32 * lda + k0),
                                             AS3(sA + s * 2048), 16, 0, 0);
#pragma unroll
        for (int s = 0; s < SN; ++s)
            __builtin_amdgcn_global_load_lds(AS1C(gB + (long long)s * 32 * ldb + k0),
                                             AS3(sB + s * 2048), 16, 0, 0);
        __syncthreads();

#pragma unroll
        for (int ks = 0; ks < 2; ++ks) {
            bf16x8 af[4], bfr[FJ];
            const int ch = ((ks * 4 + kq) ^ cro) * 8;
#pragma unroll
            for (int i = 0; i < 4; ++i)
                af[i] = *(const bf16x8*)(lA + (wm + i * 16 + lm) * 64 + ch);
#pragma unroll
            for (int j = 0; j < FJ; ++j)
                bfr[j] = *(const bf16x8*)(lB + (wn + j * 16 + lm) * 64 + ch);
#pragma unroll
            for (int i = 0; i < 4; ++i)
#pragma unroll
                for (int j = 0; j < FJ; ++j)
                    acc[i][j] = __builtin_amdgcn_mfma_f32_16x16x32_bf16(af[i], bfr[j], acc[i][j], 0, 0, 0);
        }
    }

    // epilogue: C/D layout col = lane&15, row = (lane>>4)*4 + reg  [m89]
    const bool vmode = V_SPLIT && (bn >= 2 * H_);
    const int r0q = kq * 4;

    if (EXP_SUM) {
#pragma unroll
        for (int i = 0; i < 4; ++i) {
            const int rowb = bm + wm + i * 16 + r0q;
            float ps[4] = {0.f, 0.f, 0.f, 0.f};
#pragma unroll
            for (int j = 0; j < FJ; ++j) {
                const int col = bn + wn + j * 16 + lm;
#pragma unroll
                for (int r = 0; r < 4; ++r) {
                    float e = __expf(acc[i][j][r] * scale);
                    ps[r] += e;
                    ((__hip_bfloat16*)Cout)[(long long)bz * cBatch +
                        (long long)(rowb + r) * ldc + col] = __float2bfloat16(e);
                }
            }
#pragma unroll
            for (int r = 0; r < 4; ++r) {
#pragma unroll
                for (int m = 1; m < 16; m <<= 1)
                    ps[r] += __shfl_xor(ps[r], m);
            }
            if (lm == 0) {
#pragma unroll
                for (int r = 0; r < 4; ++r)
                    atomicAdd(rsum + bz * S_ + rowb + r, ps[r]);
            }
        }
        return;
    }

#pragma unroll
    for (int i = 0; i < 4; ++i) {
        const int rowb = bm + wm + i * 16 + r0q;
        float inv[4];
        if (ROWDIV) {
            float4 rs = *(const float4*)(rsum + bz * S_ + rowb);
            inv[0] = 1.0f / rs.x; inv[1] = 1.0f / rs.y;
            inv[2] = 1.0f / rs.z; inv[3] = 1.0f / rs.w;
        }
#pragma unroll
        for (int j = 0; j < FJ; ++j) {
            const int col = bn + wn + j * 16 + lm;
            float bvv = 0.0f;
            if (HAS_BIAS) bvv = bias[col];
            if (!vmode) {
#pragma unroll
                for (int r = 0; r < 4; ++r) {
                    float val = ROWDIV ? acc[i][j][r] * inv[r]
                                       : acc[i][j][r] * scale + bvv;
                    long long idx = (long long)bz * cBatch + (long long)(rowb + r) * ldc + col;
                    if (OUT_BF16) ((__hip_bfloat16*)Cout)[idx] = __float2bfloat16(val);
                    else          ((float*)Cout)[idx] = val;
                }
            } else {
                // vtrans[b][e][s]: b = rowb>>11, s = rowb&2047 (+r contiguous), e = col-2048
                const long long ebase = (long long)((rowb >> 11) * H_ + col - 2 * H_) * S_;
                union { ushort4 u; __hip_bfloat16 h[4]; } o;
#pragma unroll
                for (int r = 0; r < 4; ++r)
                    o.h[r] = __float2bfloat16(acc[i][j][r] + bvv);
                *(ushort4*)(vtrans + ebase + (rowb & 2047)) = o.u;
            }
        }
    }
}

// ---------------- launcher ----------------
extern "C" void kernel_launch(void* const* d_in, const int* in_sizes, int n_in,
                              void* d_out, int out_size, void* d_ws, size_t ws_size,
                              hipStream_t stream)
{
    const float* X  = (const float*)d_in[0];
    const float* Wq = (const float*)d_in[1];
    const float* bq = (const float*)d_in[2];
    const float* Wk = (const float*)d_in[3];
    const float* bk = (const float*)d_in[4];
    const float* Wv = (const float*)d_in[5];
    const float* bv = (const float*)d_in[6];
    float* out = (float*)d_out;

    char* w = (char*)d_ws;
    const size_t MB = 1ull << 20;
    // Layout (~80 MB):
    //   [0,16)   Xb          (dead after QKV gemm)
    //   [16,22)  Wall bf16 [3072,1024]   (dead after QKV gemm)
    //   [22,23)  ball fp32 [3072]        (dead after QKV gemm)
    //   [0,32)   sc  exp-scores bf16 [B,S,S]   (overlays dead Xb/Wall/ball)
    //   [32,64)  qk  bf16 [8192,2048]  (Q cols 0..1023, K cols 1024..2047)
    //   [64,80)  vtb bf16 [B,H,S]  (written transposed by QKV epilogue)
    //   [80MB, +32KB) rsum fp32 [B*S]
    __hip_bfloat16* Xb   = (__hip_bfloat16*)(w + 0);
    __hip_bfloat16* Wall = (__hip_bfloat16*)(w + 16 * MB);
    float*          ball = (float*)        (w + 22 * MB);
    __hip_bfloat16* sc   = (__hip_bfloat16*)(w + 0);
    __hip_bfloat16* qk   = (__hip_bfloat16*)(w + 32 * MB);
    __hip_bfloat16* vtb  = (__hip_bfloat16*)(w + 64 * MB);
    float*          rsum = (float*)        (w + 80 * MB);

    // 1. prep (X/W convert + bias pack + rsum zero) — grid-stride @2048 blocks
    prep_k<<<2048, 256, 0, stream>>>(X, Wq, Wk, Wv, bq, bk, bv,
                                     Xb, Wall, ball, rsum);

    // 2. fused QKV projection (1536 blocks = 2 exact rounds @3/CU)
    dim3 g1(3 * H_ / 128, (B_ * S_) / 128, 1);
    gemm_bt<128, 1, true, true, true, false, false><<<g1, 256, 0, stream>>>(
        Xb, H_, 0, Wall, H_, 0, ball, qk, 2 * H_, 0, vtb, nullptr,
        B_ * S_, 3 * H_, H_, 1.0f);

    // 3. exp-scores (1024 blocks; MINW=4 -> 4 blocks/CU -> exactly 1 round)
    dim3 g2(S_ / 128, S_ / 128, B_);
    gemm_bt<128, 4, true, false, false, true, false><<<g2, 256, 0, stream>>>(
        qk,      2 * H_, (long long)S_ * 2 * H_,
        qk + H_, 2 * H_, (long long)S_ * 2 * H_,
        nullptr, sc, S_, (long long)S_ * S_, nullptr, rsum, S_, S_, H_, 0.03125f);

    // 4. out[b] = (exp-scores[b] @ vtb[b]^T) / rsum
    //    r6: BN 64 -> 128 (tile-space data: 64-wide is the worst point of this
    //    structure; staging-per-flop improves 1.75x, A-panel re-reads halve).
    //    Grid 8x16x4 = 512 blocks, all co-resident.
    dim3 g3(H_ / 128, S_ / 128, B_);
    gemm_bt<128, 4, false, false, false, false, true><<<g3, 256, 0, stream>>>(
        sc,  S_, (long long)S_ * S_,
        vtb, S_, (long long)H_ * S_,
        nullptr, out, H_, (long long)S_ * H_, nullptr, rsum, S_, H_, S_, 1.0f);
}